// Round 1
// baseline (427.066 us; speedup 1.0000x reference)
//
#include <hip/hip_runtime.h>
#include <hip/hip_bf16.h>

// GAT layer: out = elu( softmax(mask(leakyrelu(s1[i]+s2[j]))) @ (h@W) )
// N=8192, F_IN=512, F_OUT=64. HBM floor = adj stream (256 MiB) ~= 40 us.
//
// Round 4 (this session): k3 restructured —
//   (1) __launch_bounds__(512,2): VGPR cap 128->256. Grid is 2 blocks/CU
//       anyway, so this is free and removes any scratch-spill risk in the
//       16-round main loop (spill traffic there would be GBs).
//   (2) 2-round-deep adj/s2 prefetch in double register sets (A/B). bf
//       (WhT) loads are issued BEFORE the adj prefetch each round, so the
//       MFMA's s_waitcnt vmcnt(8) no longer drains the adj queue — stage()
//       consumes loads issued a full round earlier (latency fully hidden).
//   (3) stage(): exp2(fma(e,log2e,-cr*log2e)) replaces sub+mul+exp; single
//       f16x4 ds_write_b64 replaces 2x f16x2.
//
// ws layout:
//   WT   f16 [64][512]   @ 0        W transposed, f16
//   WhT  f16 [64][8192]  @ 65536    Wh transposed, f16 (MFMA B operand)
//   s1   f32 [8192]      @ 1114112
//   s2   f32 [8192]      @ 1146880

typedef _Float16 f16;
typedef _Float16 f16x2 __attribute__((ext_vector_type(2)));
typedef _Float16 f16x4 __attribute__((ext_vector_type(4)));
typedef _Float16 f16x8 __attribute__((ext_vector_type(8)));
typedef float f32x4 __attribute__((ext_vector_type(4)));
typedef int   i32x4 __attribute__((ext_vector_type(4)));

#define GAT_N 8192
#define GAT_FIN 512
#define GAT_FOUT 64
#define GAT_ALPHA 0.2f
#define GAT_L2E 1.44269504088896340736f

// ---------------- K0: W [512][64] f32 -> WT [64][512] f16 ----------------
__global__ void k0_wtrans(const float* __restrict__ W, f16* __restrict__ WT) {
    int idx = blockIdx.x * blockDim.x + threadIdx.x;   // 0..32767
    int k = idx >> 6, c = idx & 63;
    WT[c * GAT_FIN + k] = (f16)W[idx];
}

// ---------------- K1: Wh = h@W (f16 MFMA), fused s1/s2, emit WhT f16 -----
// 512 blocks x 4 waves. Wave w covers k in [w*128, (w+1)*128); partial
// accumulators combined via LDS; epilogue: wave w owns col-tile t=w.
__global__ __launch_bounds__(256) void k1_gemm(const float* __restrict__ h,
        const f16* __restrict__ WT, const float* __restrict__ a,
        f16* __restrict__ WhT, float* __restrict__ s1, float* __restrict__ s2) {
    __shared__ float pacc[4][4][64][4];     // [wave][t][lane][reg] 16 KB
    __shared__ float s1red[4][16], s2red[4][16];

    int tid = threadIdx.x;
    int w = tid >> 6, lane = tid & 63;
    int l15 = lane & 15, quad = lane >> 4;
    int rb = blockIdx.x * 16;
    size_t arow = (size_t)(rb + l15) * GAT_FIN;

    f32x4 acc[4] = {};
#pragma unroll
    for (int ks = 0; ks < 4; ks++) {
        int kb = w * 128 + ks * 32 + quad * 8;
        const float4* hp = (const float4*)(h + arow + kb);
        float4 h0 = hp[0], h1 = hp[1];
        f16x8 af = { (f16)h0.x, (f16)h0.y, (f16)h0.z, (f16)h0.w,
                     (f16)h1.x, (f16)h1.y, (f16)h1.z, (f16)h1.w };
#pragma unroll
        for (int t = 0; t < 4; t++) {
            f16x8 bf = *(const f16x8*)(WT + (t * 16 + l15) * GAT_FIN + kb);
            acc[t] = __builtin_amdgcn_mfma_f32_16x16x32_f16(af, bf, acc[t], 0, 0, 0);
        }
    }
#pragma unroll
    for (int t = 0; t < 4; t++)
        *(f32x4*)&pacc[w][t][lane][0] = acc[t];
    __syncthreads();

    // wave w finalizes col-tile t=w: C[row=quad*4+reg][col=w*16+l15]
    float a1v = a[w * 16 + l15];
    float a2v = a[GAT_FOUT + w * 16 + l15];
    float vreg[4];
#pragma unroll
    for (int reg = 0; reg < 4; reg++) {
        float v = 0.f;
#pragma unroll
        for (int ww = 0; ww < 4; ww++) v += pacc[ww][w][lane][reg];
        vreg[reg] = v;
    }
    f16x4 pk = { (f16)vreg[0], (f16)vreg[1], (f16)vreg[2], (f16)vreg[3] };
    *(f16x4*)(WhT + (size_t)(w * 16 + l15) * GAT_N + rb + quad * 4) = pk;  // 8-B store

#pragma unroll
    for (int reg = 0; reg < 4; reg++) {
        float c1 = vreg[reg] * a1v, c2 = vreg[reg] * a2v;
#pragma unroll
        for (int off = 1; off < 16; off <<= 1) {   // reduce over 16 cols (l15)
            c1 += __shfl_xor(c1, off);
            c2 += __shfl_xor(c2, off);
        }
        if (l15 == 0) { s1red[w][quad * 4 + reg] = c1; s2red[w][quad * 4 + reg] = c2; }
    }
    __syncthreads();
    if (tid < 16) {
        float t1 = 0.f, t2 = 0.f;
#pragma unroll
        for (int ww = 0; ww < 4; ww++) { t1 += s1red[ww][tid]; t2 += s2red[ww][tid]; }
        s1[rb + tid] = t1;
        s2[rb + tid] = t2;
    }
}

// ---------------- K3: fused max+mask+softmax+(P@Wh)+elu ------------------
// 512 blocks (16 rows) x 8 waves. Pre-phase: block-local max(s2) (L2-hot;
// per-row constants cancel in num/den). Main loop: each half-wave streams
// ONE adj row contiguously (nontemporal int4) with a 2-round-deep register
// prefetch; p computed at load+1 round, staged f16 into LDS in MFMA A-frag
// layout, double-buffered; MFMA against L2-resident WhT.
__global__ __launch_bounds__(512, 2) void k3_attn(const int* __restrict__ adj,
        const f16* __restrict__ WhT, const float* __restrict__ s1,
        const float* __restrict__ s2, float* __restrict__ out) {
    // pbuf: 2 x 16 steps x 520 f16; accbuf (32 KB) aliases pbuf (33,280 B)
    __shared__ __align__(16) char smem[2 * 16 * 520 * 2];
    f16* pbuf = (f16*)smem;
    float (*accbuf)[16][64] = (float (*)[16][64])smem;
    __shared__ float dbuf2[16];
    __shared__ float mred[8];

    int tid = threadIdx.x;
    int w = tid >> 6, lane = tid & 63;
    int l15 = lane & 15, quad = lane >> 4;
    int hhalf = lane >> 5, q = lane & 31;
    int rb = blockIdx.x * 16;
    int r = 2 * w + hhalf;                 // staged row (0..15), one per half-wave

    // ---- pre-phase: mxv = max(s2) (block-local) ----
    float m = -1e30f;
    for (int i = tid; i < GAT_N; i += 512) m = fmaxf(m, s2[i]);
#pragma unroll
    for (int off = 32; off >= 1; off >>= 1) m = fmaxf(m, __shfl_xor(m, off));
    if (lane == 0) mred[w] = m;
    __syncthreads();
    float mxv = mred[0];
#pragma unroll
    for (int ww = 1; ww < 8; ww++) mxv = fmaxf(mxv, mred[ww]);

    float s1r = s1[rb + r];
    float cr = s1r + mxv;
    cr = fmaxf(cr, GAT_ALPHA * cr);        // leakyrelu of row upper bound
    float mcrl = -cr * GAT_L2E;            // exp(e-cr) == exp2(e*L2E + mcrl)
    const int* adjrow = adj + (size_t)(rb + r) * GAT_N;

    float dacc = 0.f;
    f32x4 acc[4] = {};
    i32x4  avA[4], avB[4];
    float4 svA[4], svB[4];

    auto loadreg = [&](i32x4 (&av_)[4], float4 (&sv_)[4], int rd) {
#pragma unroll
        for (int p = 0; p < 4; p++) {
            int c0 = rd * 512 + p * 128 + q * 4;
            av_[p] = __builtin_nontemporal_load((const i32x4*)(adjrow + c0));
            sv_[p] = *(const float4*)(s2 + c0);
        }
    };

    // element (row r, col c) -> frag slot: step=c>>5, lane'=((c>>3)&3)*16+r, j=c&7
    auto stage = [&](const i32x4 (&av_)[4], const float4 (&sv_)[4], int bb) {
#pragma unroll
        for (int p = 0; p < 4; p++) {
            float svv[4] = { sv_[p].x, sv_[p].y, sv_[p].z, sv_[p].w };
            int base = (4 * p + (q >> 3)) * 520 + ((q >> 1) & 3) * 128 + r * 8 + (q & 1) * 4;
            f16 pf[4];
#pragma unroll
            for (int j = 0; j < 4; j++) {
                float x = s1r + svv[j];
                float e = fmaxf(x, GAT_ALPHA * x);      // leakyrelu
                float pv = exp2f(fmaf(e, GAT_L2E, mcrl));   // exponent <= ~0
                pv = (av_[p][j] > 0) ? pv : 0.0f;       // mask
                dacc += pv;
                pf[j] = (f16)pv;
            }
            f16x4 pk = { pf[0], pf[1], pf[2], pf[3] };
            *(f16x4*)&pbuf[bb * 8320 + base] = pk;      // one ds_write_b64
        }
    };

    // one K-round: MFMA over pbuf[b] (data rd), stage rd+1 from regs P,
    // prefetch rd+2 into regs F. bf loads issued FIRST so the MFMA waitcnt
    // (vmcnt(8)) leaves the adj prefetch in flight.
    auto round = [&](int rd, int b, const i32x4 (&avP)[4], const float4 (&svP)[4],
                     i32x4 (&avF)[4], float4 (&svF)[4]) {
        f16x8 bfr[2][4];
#pragma unroll
        for (int sl = 0; sl < 2; sl++) {
            int kb = rd * 512 + (2 * w + sl) * 32 + quad * 8;
#pragma unroll
            for (int t = 0; t < 4; t++)
                bfr[sl][t] = *(const f16x8*)(WhT + (size_t)(t * 16 + l15) * GAT_N + kb);
        }
        if (rd < 14) loadreg(avF, svF, rd + 2);
#pragma unroll
        for (int sl = 0; sl < 2; sl++) {
            f16x8 af = *(const f16x8*)&pbuf[b * 8320 + (2 * w + sl) * 520 + lane * 8];
#pragma unroll
            for (int t = 0; t < 4; t++)
                acc[t] = __builtin_amdgcn_mfma_f32_16x16x32_f16(af, bfr[sl][t], acc[t], 0, 0, 0);
        }
        if (rd < 15) stage(avP, svP, 1 - b);
        __syncthreads();
    };

    // prologue: rd0 -> regs A -> pbuf[0]; rd1 -> regs B
    loadreg(avA, svA, 0);
    stage(avA, svA, 0);
    loadreg(avB, svB, 1);
    __syncthreads();

#pragma unroll 1
    for (int rd = 0; rd < 16; rd += 2) {
        round(rd,     0, avB, svB, avA, svA);   // even: consume-stage B, refill A
        round(rd + 1, 1, avA, svA, avB, svB);   // odd:  consume-stage A, refill B
    }

    // epilogue: accbuf aliases pbuf — safe, all MFMA reads behind the barrier
#pragma unroll
    for (int t = 0; t < 4; t++)
#pragma unroll
        for (int reg = 0; reg < 4; reg++)
            accbuf[w][quad * 4 + reg][t * 16 + l15] = acc[t][reg];
#pragma unroll
    for (int off = 16; off >= 1; off >>= 1) dacc += __shfl_xor(dacc, off);
    if (q == 0) dbuf2[r] = dacc;
    __syncthreads();

    for (int o = tid; o < 16 * 64; o += 512) {
        int rr = o >> 6, c = o & 63;
        float num = 0.f;
#pragma unroll
        for (int ww = 0; ww < 8; ww++) num += accbuf[ww][rr][c];
        float hp = num / dbuf2[rr];
        out[(size_t)(rb + rr) * GAT_FOUT + c] = hp > 0.f ? hp : expm1f(hp);
    }
}

// ---------------- launch -------------------------------------------------
extern "C" void kernel_launch(void* const* d_in, const int* in_sizes, int n_in,
                              void* d_out, int out_size, void* d_ws, size_t ws_size,
                              hipStream_t stream) {
    const float* h   = (const float*)d_in[0];
    const float* W   = (const float*)d_in[1];
    const float* a   = (const float*)d_in[2];
    const int*   adj = (const int*)d_in[3];
    float* out = (float*)d_out;

    char* ws = (char*)d_ws;
    f16*   WT  = (f16*)ws;
    f16*   WhT = (f16*)(ws + 65536);
    float* s1  = (float*)(ws + 65536 + 1048576);
    float* s2  = (float*)(ws + 65536 + 1048576 + 32768);

    k0_wtrans<<<128, 256, 0, stream>>>(W, WT);
    k1_gemm<<<512, 256, 0, stream>>>(h, WT, a, WhT, s1, s2);
    k3_attn<<<512, 512, 0, stream>>>(adj, WhT, s1, s2, out);
}

// Round 2
// 406.127 us; speedup vs baseline: 1.0516x; 1.0516x over previous
//
#include <hip/hip_runtime.h>
#include <hip/hip_bf16.h>

// GAT layer: out = elu( softmax(mask(leakyrelu(s1[i]+s2[j]))) @ (h@W) )
// N=8192, F_IN=512, F_OUT=64. HBM floor = adj stream (256 MiB) ~= 40 us.
//
// Round 5 (this session): k3 barrier + occupancy fix —
//   (1) Per-round __syncthreads() (which forces s_waitcnt vmcnt(0) before
//       s_barrier, draining the adj prefetch queue every round) replaced by
//       lgkmcnt(0)-only + raw s_barrier. LDS double-buffer correctness only
//       needs LDS ops drained; adj/s2 NT global loads now survive barriers,
//       so the A/B register prefetch gets ~2 phases of latency cover.
//   (2) Back to 2 blocks/CU: s2 moved to LDS (staged once in pre-phase,
//       broadcast ds_read_b128 in stage) saving 32 prefetch VGPRs; bf loads
//       back to just-in-time; __launch_bounds__(512,4) caps VGPR at 128.
//       LDS 33.3K(pbuf) + 32K(s2l) = 66K -> 2 blocks/CU = 132K <= 160K.
//   (3) vmcnt FIFO discipline per phase: bf loads first, then adj (rd+2/3),
//       then stage consumes the adj set issued 2 phases earlier -> its wait
//       is vmcnt(~12), never draining the in-flight prefetch.
//
// ws layout:
//   WT   f16 [64][512]   @ 0        W transposed, f16
//   WhT  f16 [64][8192]  @ 65536    Wh transposed, f16 (MFMA B operand)
//   s1   f32 [8192]      @ 1114112
//   s2   f32 [8192]      @ 1146880

typedef _Float16 f16;
typedef _Float16 f16x2 __attribute__((ext_vector_type(2)));
typedef _Float16 f16x4 __attribute__((ext_vector_type(4)));
typedef _Float16 f16x8 __attribute__((ext_vector_type(8)));
typedef float f32x4 __attribute__((ext_vector_type(4)));
typedef int   i32x4 __attribute__((ext_vector_type(4)));

#define GAT_N 8192
#define GAT_FIN 512
#define GAT_FOUT 64
#define GAT_ALPHA 0.2f
#define GAT_L2E 1.44269504088896340736f

// lgkmcnt-only barrier: LDS writes/reads drained, global loads stay in
// flight. asm memory clobbers fence the compiler on both sides.
#define BAR_LGKM() do { \
    asm volatile("s_waitcnt lgkmcnt(0)" ::: "memory"); \
    __builtin_amdgcn_s_barrier(); \
    asm volatile("" ::: "memory"); \
} while (0)

// ---------------- K0: W [512][64] f32 -> WT [64][512] f16 ----------------
__global__ void k0_wtrans(const float* __restrict__ W, f16* __restrict__ WT) {
    int idx = blockIdx.x * blockDim.x + threadIdx.x;   // 0..32767
    int k = idx >> 6, c = idx & 63;
    WT[c * GAT_FIN + k] = (f16)W[idx];
}

// ---------------- K1: Wh = h@W (f16 MFMA), fused s1/s2, emit WhT f16 -----
// 512 blocks x 4 waves. Wave w covers k in [w*128, (w+1)*128); partial
// accumulators combined via LDS; epilogue: wave w owns col-tile t=w.
__global__ __launch_bounds__(256) void k1_gemm(const float* __restrict__ h,
        const f16* __restrict__ WT, const float* __restrict__ a,
        f16* __restrict__ WhT, float* __restrict__ s1, float* __restrict__ s2) {
    __shared__ float pacc[4][4][64][4];     // [wave][t][lane][reg] 16 KB
    __shared__ float s1red[4][16], s2red[4][16];

    int tid = threadIdx.x;
    int w = tid >> 6, lane = tid & 63;
    int l15 = lane & 15, quad = lane >> 4;
    int rb = blockIdx.x * 16;
    size_t arow = (size_t)(rb + l15) * GAT_FIN;

    f32x4 acc[4] = {};
#pragma unroll
    for (int ks = 0; ks < 4; ks++) {
        int kb = w * 128 + ks * 32 + quad * 8;
        const float4* hp = (const float4*)(h + arow + kb);
        float4 h0 = hp[0], h1 = hp[1];
        f16x8 af = { (f16)h0.x, (f16)h0.y, (f16)h0.z, (f16)h0.w,
                     (f16)h1.x, (f16)h1.y, (f16)h1.z, (f16)h1.w };
#pragma unroll
        for (int t = 0; t < 4; t++) {
            f16x8 bf = *(const f16x8*)(WT + (t * 16 + l15) * GAT_FIN + kb);
            acc[t] = __builtin_amdgcn_mfma_f32_16x16x32_f16(af, bf, acc[t], 0, 0, 0);
        }
    }
#pragma unroll
    for (int t = 0; t < 4; t++)
        *(f32x4*)&pacc[w][t][lane][0] = acc[t];
    __syncthreads();

    // wave w finalizes col-tile t=w: C[row=quad*4+reg][col=w*16+l15]
    float a1v = a[w * 16 + l15];
    float a2v = a[GAT_FOUT + w * 16 + l15];
    float vreg[4];
#pragma unroll
    for (int reg = 0; reg < 4; reg++) {
        float v = 0.f;
#pragma unroll
        for (int ww = 0; ww < 4; ww++) v += pacc[ww][w][lane][reg];
        vreg[reg] = v;
    }
    f16x4 pk = { (f16)vreg[0], (f16)vreg[1], (f16)vreg[2], (f16)vreg[3] };
    *(f16x4*)(WhT + (size_t)(w * 16 + l15) * GAT_N + rb + quad * 4) = pk;  // 8-B store

#pragma unroll
    for (int reg = 0; reg < 4; reg++) {
        float c1 = vreg[reg] * a1v, c2 = vreg[reg] * a2v;
#pragma unroll
        for (int off = 1; off < 16; off <<= 1) {   // reduce over 16 cols (l15)
            c1 += __shfl_xor(c1, off);
            c2 += __shfl_xor(c2, off);
        }
        if (l15 == 0) { s1red[w][quad * 4 + reg] = c1; s2red[w][quad * 4 + reg] = c2; }
    }
    __syncthreads();
    if (tid < 16) {
        float t1 = 0.f, t2 = 0.f;
#pragma unroll
        for (int ww = 0; ww < 4; ww++) { t1 += s1red[ww][tid]; t2 += s2red[ww][tid]; }
        s1[rb + tid] = t1;
        s2[rb + tid] = t2;
    }
}

// ---------------- K3: fused max+mask+softmax+(P@Wh)+elu ------------------
// 512 blocks (16 rows) x 8 waves, 2 blocks/CU. Pre-phase: block-local
// max(s2) + s2 -> LDS. Main loop: each half-wave streams ONE adj row
// contiguously (nontemporal int4) with a 2-phase-deep register prefetch
// that survives barriers (lgkmcnt-only); p computed at stage, f16 into LDS
// in MFMA A-frag layout, double-buffered; MFMA against L2-resident WhT.
__global__ __launch_bounds__(512, 4) void k3_attn(const int* __restrict__ adj,
        const f16* __restrict__ WhT, const float* __restrict__ s1,
        const float* __restrict__ s2, float* __restrict__ out) {
    // pbuf: 2 x 16 steps x 520 f16; accbuf (32 KB) aliases pbuf (33,280 B)
    __shared__ __align__(16) char smem[2 * 16 * 520 * 2];
    f16* pbuf = (f16*)smem;
    float (*accbuf)[16][64] = (float (*)[16][64])smem;
    __shared__ __align__(16) float s2l[GAT_N];   // 32 KB, L2->LDS once
    __shared__ float dbuf2[16];
    __shared__ float mred[8];

    int tid = threadIdx.x;
    int w = tid >> 6, lane = tid & 63;
    int l15 = lane & 15, quad = lane >> 4;
    int hhalf = lane >> 5, q = lane & 31;
    int rb = blockIdx.x * 16;
    int r = 2 * w + hhalf;                 // staged row (0..15), one per half-wave

    // ---- pre-phase: mxv = max(s2) (block-local) + stage s2 into LDS ----
    float m = -1e30f;
    for (int i = tid; i < GAT_N; i += 512) {
        float v = s2[i];
        s2l[i] = v;
        m = fmaxf(m, v);
    }
#pragma unroll
    for (int off = 32; off >= 1; off >>= 1) m = fmaxf(m, __shfl_xor(m, off));
    if (lane == 0) mred[w] = m;
    __syncthreads();
    float mxv = mred[0];
#pragma unroll
    for (int ww = 1; ww < 8; ww++) mxv = fmaxf(mxv, mred[ww]);

    float s1r = s1[rb + r];
    float cr = s1r + mxv;
    cr = fmaxf(cr, GAT_ALPHA * cr);        // leakyrelu of row upper bound
    float mcrl = -cr * GAT_L2E;            // exp(e-cr) == exp2(e*L2E + mcrl)
    const int* adjrow = adj + (size_t)(rb + r) * GAT_N;

    float dacc = 0.f;
    f32x4 acc[4] = {};
    i32x4 avA[4], avB[4];                  // 2-phase-deep adj prefetch

    auto loadadj = [&](i32x4 (&av_)[4], int rd) {
#pragma unroll
        for (int p = 0; p < 4; p++)
            av_[p] = __builtin_nontemporal_load(
                (const i32x4*)(adjrow + rd * 512 + p * 128 + q * 4));
    };

    // element (row r, col c) -> frag slot: step=c>>5, lane'=((c>>3)&3)*16+r, j=c&7
    auto stage = [&](const i32x4 (&av_)[4], int rdS, int bb) {
#pragma unroll
        for (int p = 0; p < 4; p++) {
            int c0 = rdS * 512 + p * 128 + q * 4;
            float4 sv4 = *(const float4*)&s2l[c0];   // broadcast across half-waves
            float svv[4] = { sv4.x, sv4.y, sv4.z, sv4.w };
            int base = (4 * p + (q >> 3)) * 520 + ((q >> 1) & 3) * 128 + r * 8 + (q & 1) * 4;
            f16 pf[4];
#pragma unroll
            for (int j = 0; j < 4; j++) {
                float x = s1r + svv[j];
                float e = fmaxf(x, GAT_ALPHA * x);          // leakyrelu
                float pv = exp2f(fmaf(e, GAT_L2E, mcrl));   // exponent <= ~0
                pv = (av_[p][j] > 0) ? pv : 0.0f;           // mask
                dacc += pv;
                pf[j] = (f16)pv;
            }
            f16x4 pk = { pf[0], pf[1], pf[2], pf[3] };
            *(f16x4*)&pbuf[bb * 8320 + base] = pk;          // one ds_write_b64
        }
    };

    auto mmaround = [&](int rd, int b) {
#pragma unroll
        for (int sl = 0; sl < 2; sl++) {
            f16x8 af = *(const f16x8*)&pbuf[b * 8320 + (2 * w + sl) * 520 + lane * 8];
            int kb = rd * 512 + (2 * w + sl) * 32 + quad * 8;
#pragma unroll
            for (int t = 0; t < 4; t++) {
                f16x8 bf = *(const f16x8*)(WhT + (size_t)(t * 16 + l15) * GAT_N + kb);
                acc[t] = __builtin_amdgcn_mfma_f32_16x16x32_f16(af, bf, acc[t], 0, 0, 0);
            }
        }
    };

    // prologue: rd0 -> A -> pbuf[0]; rd1 -> B (in flight across barrier)
    loadadj(avA, 0);
    stage(avA, 0, 0);
    loadadj(avB, 1);
    BAR_LGKM();

#pragma unroll 1
    for (int rd = 0; rd < 16; rd += 2) {
        // even phase: consume buf0(rd); refill A with rd+2; stage B(rd+1)->buf1
        mmaround(rd, 0);
        if (rd + 2 < 16) loadadj(avA, rd + 2);
        stage(avB, rd + 1, 1);
        BAR_LGKM();
        // odd phase: consume buf1(rd+1); refill B with rd+3; stage A(rd+2)->buf0
        mmaround(rd + 1, 1);
        if (rd + 3 < 16) loadadj(avB, rd + 3);
        if (rd + 2 < 16) stage(avA, rd + 2, 0);
        BAR_LGKM();
    }

    // epilogue: accbuf aliases pbuf — safe, all MFMA reads behind the barrier
#pragma unroll
    for (int t = 0; t < 4; t++)
#pragma unroll
        for (int reg = 0; reg < 4; reg++)
            accbuf[w][quad * 4 + reg][t * 16 + l15] = acc[t][reg];
#pragma unroll
    for (int off = 16; off >= 1; off >>= 1) dacc += __shfl_xor(dacc, off);
    if (q == 0) dbuf2[r] = dacc;
    __syncthreads();

    for (int o = tid; o < 16 * 64; o += 512) {
        int rr = o >> 6, c = o & 63;
        float num = 0.f;
#pragma unroll
        for (int ww = 0; ww < 8; ww++) num += accbuf[ww][rr][c];
        float hp = num / dbuf2[rr];
        out[(size_t)(rb + rr) * GAT_FOUT + c] = hp > 0.f ? hp : expm1f(hp);
    }
}

// ---------------- launch -------------------------------------------------
extern "C" void kernel_launch(void* const* d_in, const int* in_sizes, int n_in,
                              void* d_out, int out_size, void* d_ws, size_t ws_size,
                              hipStream_t stream) {
    const float* h   = (const float*)d_in[0];
    const float* W   = (const float*)d_in[1];
    const float* a   = (const float*)d_in[2];
    const int*   adj = (const int*)d_in[3];
    float* out = (float*)d_out;

    char* ws = (char*)d_ws;
    f16*   WT  = (f16*)ws;
    f16*   WhT = (f16*)(ws + 65536);
    float* s1  = (float*)(ws + 65536 + 1048576);
    float* s2  = (float*)(ws + 65536 + 1048576 + 32768);

    k0_wtrans<<<128, 256, 0, stream>>>(W, WT);
    k1_gemm<<<512, 256, 0, stream>>>(h, WT, a, WhT, s1, s2);
    k3_attn<<<512, 512, 0, stream>>>(adj, WhT, s1, s2, out);
}